// Round 10
// baseline (84.688 us; speedup 1.0000x reference)
//
#include <hip/hip_runtime.h>

#define HW 25600
#define TS 16    // spatial locations per tile
#define NBLK 800 // blocks; each handles tiles {u, u+800}

typedef float  f32x4   __attribute__((ext_vector_type(4)));
typedef short  short8  __attribute__((ext_vector_type(8)));
typedef short  short4v __attribute__((ext_vector_type(4)));
typedef unsigned int uint2v __attribute__((ext_vector_type(2)));
typedef unsigned int uint4v __attribute__((ext_vector_type(4)));

__device__ __forceinline__ float bf2f(short h) {
    return __builtin_bit_cast(float, (unsigned)((unsigned short)h) << 16);
}
// HW packed f32->bf16 (RNE): D.lo = bf16(a), D.hi = bf16(b)
__device__ __forceinline__ unsigned cvt_pk(float a, float b) {
    unsigned r;
    asm("v_cvt_pk_bf16_f32 %0, %1, %2" : "=v"(r) : "v"(a), "v"(b));
    return r;
}

typedef __attribute__((address_space(3))) const char lds_cchar;
typedef __attribute__((address_space(3))) char lds_char;
typedef __attribute__((address_space(1))) const void g_cvoid;
__device__ __forceinline__ unsigned lds_u32(const void* p) {
    return (unsigned)(uintptr_t)(lds_cchar*)p;
}
// Async global->LDS DMA, 16B/lane. Dest = lds_base + lane*16 (linear);
// global source address is per-lane. No VGPR destination => no spill pressure.
__device__ __forceinline__ void dma16(const float* g, unsigned lds_byte) {
    __builtin_amdgcn_global_load_lds(
        (g_cvoid*)g,
        (__attribute__((address_space(3))) void*)(lds_char*)(uintptr_t)lds_byte,
        16, 0, 0);
}

// ds_read_b64_tr_b16: lane addr = tile_base(128B-aligned) + lane16*8.
// Elem j = bf16 at tile_base + lane16*2 + j*32. offset:128 -> next 4 rows.
__device__ __forceinline__ short4v tr_read(unsigned a) {
    short4v d;
    asm volatile("ds_read_b64_tr_b16 %0, %1" : "=v"(d) : "v"(a) : "memory");
    return d;
}
__device__ __forceinline__ short4v tr_read128(unsigned a) {
    short4v d;
    asm volatile("ds_read_b64_tr_b16 %0, %1 offset:128" : "=v"(d) : "v"(a) : "memory");
    return d;
}
__device__ __forceinline__ uint4v lds_b128(unsigned a) {
    uint4v d;
    asm volatile("ds_read_b128 %0, %1" : "=v"(d) : "v"(a) : "memory");
    return d;
}
// Counted lgkm waits for the 2-deep DS pipelines (rule #18: SB(0) after).
__device__ __forceinline__ void wait_lgkm8() {
    asm volatile("s_waitcnt lgkmcnt(8)" ::: "memory");
    __builtin_amdgcn_sched_barrier(0);
}
__device__ __forceinline__ void wait_lgkm6() {
    asm volatile("s_waitcnt lgkmcnt(6)" ::: "memory");
    __builtin_amdgcn_sched_barrier(0);
}
__device__ __forceinline__ void wait_lgkm0() {
    asm volatile("s_waitcnt lgkmcnt(0)" ::: "memory");
    __builtin_amdgcn_sched_barrier(0);
}
// Barrier that drains only LDS ops; VMEM (DMA, stores) stays in flight.
__device__ __forceinline__ void bar_lgkm() {
    asm volatile("s_waitcnt lgkmcnt(0)" ::: "memory");
    __builtin_amdgcn_s_barrier();
    asm volatile("" ::: "memory");
}

// 8-read tr cluster: 4 tiles (t=0..3) x (lo, hi)
struct Clu { short4v lo0, hi0, lo1, hi1, lo2, hi2, lo3, hi3; };
__device__ __forceinline__ void issue_clu(Clu& C, unsigned base, int tstride) {
    C.lo0 = tr_read(base);                C.hi0 = tr_read128(base);
    C.lo1 = tr_read(base + tstride);      C.hi1 = tr_read128(base + tstride);
    C.lo2 = tr_read(base + 2 * tstride);  C.hi2 = tr_read128(base + 2 * tstride);
    C.lo3 = tr_read(base + 3 * tstride);  C.hi3 = tr_read128(base + 3 * tstride);
}
__device__ __forceinline__ short8 mk8(short4v lo, short4v hi) {
    return __builtin_shufflevector(lo, hi, 0, 1, 2, 3, 4, 5, 6, 7);
}

// LDS layout (bytes), 81920 total == 80KB -> 2 blocks/CU (the TLP lever):
//  Xbf  [4][256][16] bf16   0     .. 32768   feats (b-major), bf16
//  fbf  [64][128]   bf16    32768 .. 49152   f (conv out), swizzle c^(s<<3)^(t<<5)
//  Rbf  [4][128][16] bf16   49152 .. 65536   retrieved
//  land 2 x 8KB             65536 .. 81920   rolling DMA chunk buffers
//  sc   [32][16] f32        aliases 65536    (land dead scores->retrieved)
__global__ __launch_bounds__(512, 2) void mmf_kernel(
    const float* __restrict__ feat0, const float* __restrict__ feat1,
    const float* __restrict__ adapter, const float* __restrict__ conv_w,
    const float* __restrict__ conv_b, const float* __restrict__ mlp_w,
    const float* __restrict__ mlp_b, float* __restrict__ out)
{
    __shared__ __align__(128) char smem[81920];
    short* Xbf = (short*)smem;
    short* fbf = (short*)(smem + 32768);
    short* Rbf = (short*)(smem + 49152);
    float* sc  = (float*)(smem + 65536);   // aliases land buf0 head

    const int tid = threadIdx.x;
    const int bid = blockIdx.x;
    // swizzle: consecutive bids land on different XCDs (hw RR); bids 8 apart
    // (same XCD, co-dispatched) get ADJACENT tiles -> both 64B halves of each
    // 128B HBM line are consumed concurrently from one L2 fetch (R1/R5-proven).
    const int u  = (bid & 7) * 100 + (bid >> 3);   // 800 = 8*100, bijective
    const int w  = __builtin_amdgcn_readfirstlane(tid >> 6); // wave id
    const int l  = tid & 63;
    const int g  = l >> 4;        // k-group within fragment
    const int sl = l & 15;        // row/col-within-tile lane index
    const int c0 = w * 16;

    const unsigned xbase    = lds_u32(Xbf);
    const unsigned landbase = lds_u32(smem + 65536);

    // global source for chunk i (512 float4 granules/chunk; granule = tid)
    auto gsrc = [&](int i, int S) -> const float* {
        int idx = i * 512 + tid;
        int q  = idx & 3;
        int r  = idx >> 2;
        int cc = r & 127;
        int b  = (r >> 7) & 3;
        int m  = r >> 9;
        const float* fp = m ? feat1 : feat0;
        return fp + (size_t)((b * 128 + cc) * HW + S + q * 4);
    };

    // ---------------- prologue: kick tile0 chunks 0,1; build weights --------
    const int S0 = u * TS;
    dma16(gsrc(0, S0), landbase + (unsigned)(tid * 16));
    dma16(gsrc(1, S0), landbase + 8192u + (unsigned)(tid * 16));

    short8 afc[8];
    #pragma unroll
    for (int ks = 0; ks < 8; ++ks) {
        const int k0 = ks * 32 + g * 8;
        const float4 w0 = *reinterpret_cast<const float4*>(conv_w + (c0 + sl) * 256 + k0);
        const float4 w1 = *reinterpret_cast<const float4*>(conv_w + (c0 + sl) * 256 + k0 + 4);
        const float4 a0 = *reinterpret_cast<const float4*>(adapter + k0);
        const float4 a1 = *reinterpret_cast<const float4*>(adapter + k0 + 4);
        uint4v au;
        au[0] = cvt_pk(w0.x * a0.x, w0.y * a0.y);
        au[1] = cvt_pk(w0.z * a0.z, w0.w * a0.w);
        au[2] = cvt_pk(w1.x * a1.x, w1.y * a1.y);
        au[3] = cvt_pk(w1.z * a1.z, w1.w * a1.w);
        afc[ks] = __builtin_bit_cast(short8, au);
    }
    short8 afm[4];
    #pragma unroll
    for (int ks = 0; ks < 4; ++ks) {
        const int k0 = ks * 32 + g * 8;
        const float4 w0 = *reinterpret_cast<const float4*>(mlp_w + (c0 + sl) * 128 + k0);
        const float4 w1 = *reinterpret_cast<const float4*>(mlp_w + (c0 + sl) * 128 + k0 + 4);
        uint4v au;
        au[0] = cvt_pk(w0.x, w0.y);
        au[1] = cvt_pk(w0.z, w0.w);
        au[2] = cvt_pk(w1.x, w1.y);
        au[3] = cvt_pk(w1.z, w1.w);
        afm[ks] = __builtin_bit_cast(short8, au);
    }
    float bias[4], mb[4];
    #pragma unroll
    for (int i = 0; i < 4; ++i) {
        bias[i] = conv_b[c0 + g * 4 + i];
        mb[i]   = mlp_b[c0 + g * 4 + i];
    }

    #pragma unroll
    for (int t = 0; t < 2; ++t) {
        const int S = (u + t * 800) * TS;

        // ---- staging: rolling DMA->convert pipeline, 8 chunks x 8KB --------
        // Slots are THREAD-private (dest = tid*16), so per-thread counted
        // vmcnt waits are exact and no barriers are needed inside the loop.
        // First wait also drains the previous tile's output stores (harmless).
        if (t > 0) {
            dma16(gsrc(0, S), landbase + (unsigned)(tid * 16));
            dma16(gsrc(1, S), landbase + 8192u + (unsigned)(tid * 16));
        }
        #pragma unroll
        for (int i = 0; i < 8; ++i) {
            if (i < 7) { asm volatile("s_waitcnt vmcnt(1)" ::: "memory"); }
            else       { asm volatile("s_waitcnt vmcnt(0)" ::: "memory"); }
            __builtin_amdgcn_sched_barrier(0);
            const float4 v = *reinterpret_cast<const float4*>(
                smem + 65536 + (i & 1) * 8192 + tid * 16);
            // ds_read must complete before re-issuing DMA into this slot
            asm volatile("s_waitcnt lgkmcnt(0)" ::: "memory");
            __builtin_amdgcn_sched_barrier(0);
            if (i < 6)
                dma16(gsrc(i + 2, S),
                      landbase + (unsigned)((i & 1) * 8192) + (unsigned)(tid * 16));
            int idx = i * 512 + tid;
            int q  = idx & 3;
            int r  = idx >> 2;
            int cc = r & 127;
            int b  = (r >> 7) & 3;
            int m  = r >> 9;
            uint2v xv;
            xv[0] = cvt_pk(v.x, v.y);
            xv[1] = cvt_pk(v.z, v.w);
            *reinterpret_cast<uint2v*>(Xbf + b * 4096 + (m * 128 + cc) * 16 + q * 4) = xv;
        }
        bar_lgkm();   // Xbf visible to all waves

        // ---------------- conv via MFMA, 2-deep pipelined tr clusters --------
        {
            f32x4 acc[4] = {{0,0,0,0},{0,0,0,0},{0,0,0,0},{0,0,0,0}};
            Clu cA, cB;
            issue_clu(cA, xbase + 0 * 1024 + g * 256 + sl * 8, 8192);
            #pragma unroll
            for (int ks = 0; ks < 8; ++ks) {
                Clu& cur = (ks & 1) ? cB : cA;
                Clu& nxt = (ks & 1) ? cA : cB;
                if (ks < 7) {
                    issue_clu(nxt, xbase + (ks + 1) * 1024 + g * 256 + sl * 8, 8192);
                    wait_lgkm8();
                } else {
                    wait_lgkm0();
                }
                acc[0] = __builtin_amdgcn_mfma_f32_16x16x32_bf16(afc[ks], mk8(cur.lo0, cur.hi0), acc[0], 0, 0, 0);
                acc[1] = __builtin_amdgcn_mfma_f32_16x16x32_bf16(afc[ks], mk8(cur.lo1, cur.hi1), acc[1], 0, 0, 0);
                acc[2] = __builtin_amdgcn_mfma_f32_16x16x32_bf16(afc[ks], mk8(cur.lo2, cur.hi2), acc[2], 0, 0, 0);
                acc[3] = __builtin_amdgcn_mfma_f32_16x16x32_bf16(afc[ks], mk8(cur.lo3, cur.hi3), acc[3], 0, 0, 0);
            }
            #pragma unroll
            for (int tt = 0; tt < 4; ++tt) {
                const int col = tt * 16 + sl;
                uint2v fu;
                fu[0] = cvt_pk(acc[tt][0] + bias[0], acc[tt][1] + bias[1]);
                fu[1] = cvt_pk(acc[tt][2] + bias[2], acc[tt][3] + bias[3]);
                *reinterpret_cast<uint2v*>(fbf + col * 128 + (((c0 + g * 4) ^ (sl << 3)) ^ (tt << 5))) = fu;
            }
        }
        bar_lgkm();

        // -------- scores via MFMA + in-register softmax ----------------------
        {
            const int sm_m = w >> 2;
            const int sm_b = w & 3;
            const int ad = sl >> 2;
            const int aq = sl & 3;
            const unsigned fbase = lds_u32(fbf);
            const unsigned btile = xbase + sm_b * 8192 + sm_m * 4096 + g * 256 + sl * 8;
            f32x4 accS[4] = {{0,0,0,0},{0,0,0,0},{0,0,0,0},{0,0,0,0}};
            struct SC { short4v blo, bhi; uint4v a0, a1, a2, a3; };
            SC pA, pB;
            auto issue = [&](SC& Sv, int kk) {
                const unsigned bt = btile + (unsigned)(kk * 1024);
                Sv.blo = tr_read(bt); Sv.bhi = tr_read128(bt);
                const int cg = kk * 4 + g;
                Sv.a0 = lds_b128(fbase + (unsigned)((ad * 16 + 0 + aq) * 256 + (((cg ^ (0 + aq)) ^ (ad << 2)) << 4)));
                Sv.a1 = lds_b128(fbase + (unsigned)((ad * 16 + 4 + aq) * 256 + (((cg ^ (4 + aq)) ^ (ad << 2)) << 4)));
                Sv.a2 = lds_b128(fbase + (unsigned)((ad * 16 + 8 + aq) * 256 + (((cg ^ (8 + aq)) ^ (ad << 2)) << 4)));
                Sv.a3 = lds_b128(fbase + (unsigned)((ad * 16 + 12 + aq) * 256 + (((cg ^ (12 + aq)) ^ (ad << 2)) << 4)));
            };
            issue(pA, 0);
            #pragma unroll
            for (int kk = 0; kk < 4; ++kk) {
                SC& cur = (kk & 1) ? pB : pA;
                SC& nxt = (kk & 1) ? pA : pB;
                if (kk < 3) {
                    issue(nxt, kk + 1);
                    wait_lgkm6();
                } else {
                    wait_lgkm0();
                }
                const short8 bf = mk8(cur.blo, cur.bhi);
                accS[0] = __builtin_amdgcn_mfma_f32_16x16x32_bf16(__builtin_bit_cast(short8, cur.a0), bf, accS[0], 0, 0, 0);
                accS[1] = __builtin_amdgcn_mfma_f32_16x16x32_bf16(__builtin_bit_cast(short8, cur.a1), bf, accS[1], 0, 0, 0);
                accS[2] = __builtin_amdgcn_mfma_f32_16x16x32_bf16(__builtin_bit_cast(short8, cur.a2), bf, accS[2], 0, 0, 0);
                accS[3] = __builtin_amdgcn_mfma_f32_16x16x32_bf16(__builtin_bit_cast(short8, cur.a3), bf, accS[3], 0, 0, 0);
            }
            const int cstar = sl >> 2, qstar = sl & 3;
            float x = accS[0][0];
            #pragma unroll
            for (int c = 0; c < 4; ++c)
                #pragma unroll
                for (int q = 0; q < 4; ++q)
                    if (c == cstar && q == qstar) x = accS[c][q];
            x *= 0.088388347648318447f;   // 1/sqrt(128)
            float mx = fmaxf(x, __shfl_xor(x, 16));
            mx = fmaxf(mx, __shfl_xor(mx, 32));
            float e = __expf(x - mx);
            float sm = e + __shfl_xor(e, 16);
            sm += __shfl_xor(sm, 32);
            sc[(sm_m * 16 + sm_b * 4 + g) * 16 + sl] = e / sm;
        }
        bar_lgkm();

        // ---------------- retrieved[col][cc] = sum_d aw[d]*f[(d,s)][cc] -----
        {
            const int b = l >> 4, s = l & 15;
            float aw[4];
            #pragma unroll
            for (int d = 0; d < 4; ++d)
                aw[d] = sc[(b * 4 + d) * 16 + s] + sc[(16 + b * 4 + d) * 16 + s];
            #pragma unroll
            for (int h = 0; h < 2; ++h) {
                const int cb = w * 2 + h;
                float r[8] = {0,0,0,0,0,0,0,0};
                #pragma unroll
                for (int d = 0; d < 4; ++d) {
                    const int colf = d * 16 + s;
                    short8 fv = *reinterpret_cast<const short8*>(
                        fbf + colf * 128 + (((cb ^ s) ^ (d << 2)) << 3));
                    #pragma unroll
                    for (int e = 0; e < 8; ++e) r[e] += aw[d] * bf2f(fv[e]);
                }
                #pragma unroll
                for (int e = 0; e < 8; e += 2) {
                    unsigned uu = cvt_pk(r[e], r[e + 1]);
                    Rbf[b * 2048 + (cb * 8 + e) * 16 + s]     = (short)(uu & 0xffffu);
                    Rbf[b * 2048 + (cb * 8 + e + 1) * 16 + s] = (short)(uu >> 16);
                }
            }
        }
        bar_lgkm();

        // ---------------- MLP via MFMA + relu + residual + out ---------------
        {
            f32x4 acc[4] = {{0,0,0,0},{0,0,0,0},{0,0,0,0},{0,0,0,0}};
            const unsigned rbase = lds_u32(Rbf);
            Clu cA, cB;
            issue_clu(cA, rbase + 0 * 1024 + g * 256 + sl * 8, 4096);
            #pragma unroll
            for (int ks = 0; ks < 4; ++ks) {
                Clu& cur = (ks & 1) ? cB : cA;
                Clu& nxt = (ks & 1) ? cA : cB;
                if (ks < 3) {
                    issue_clu(nxt, rbase + (ks + 1) * 1024 + g * 256 + sl * 8, 4096);
                    wait_lgkm8();
                } else {
                    wait_lgkm0();
                }
                acc[0] = __builtin_amdgcn_mfma_f32_16x16x32_bf16(afm[ks], mk8(cur.lo0, cur.hi0), acc[0], 0, 0, 0);
                acc[1] = __builtin_amdgcn_mfma_f32_16x16x32_bf16(afm[ks], mk8(cur.lo1, cur.hi1), acc[1], 0, 0, 0);
                acc[2] = __builtin_amdgcn_mfma_f32_16x16x32_bf16(afm[ks], mk8(cur.lo2, cur.hi2), acc[2], 0, 0, 0);
                acc[3] = __builtin_amdgcn_mfma_f32_16x16x32_bf16(afm[ks], mk8(cur.lo3, cur.hi3), acc[3], 0, 0, 0);
            }
            // stores issue unwaited; the next tile's first staging vmcnt wait
            // (or s_endpgm) drains them off the critical path.
            #pragma unroll
            for (int tt = 0; tt < 4; ++tt) {
                const int col = tt * 16 + sl;    // b = tt, s = sl
                const short4v res = *reinterpret_cast<const short4v*>(
                    fbf + col * 128 + (((c0 + g * 4) ^ (sl << 3)) ^ (tt << 5)));
                #pragma unroll
                for (int i = 0; i < 4; ++i) {
                    const int c = c0 + g * 4 + i;
                    float v = fmaxf(acc[tt][i] + mb[i], 0.f) + bf2f(res[i]);
                    out[(size_t)(tt * 128 + c) * HW + S + sl] = v;
                }
            }
        }
        // next staging writes Xbf/land only (disjoint from fbf/Rbf reads done
        // above per-wave); the staging-end barrier re-syncs before conv.
        if (t == 0) bar_lgkm();
    }
}

extern "C" void kernel_launch(void* const* d_in, const int* in_sizes, int n_in,
                              void* d_out, int out_size, void* d_ws, size_t ws_size,
                              hipStream_t stream) {
    const float* feat0   = (const float*)d_in[0];
    const float* feat1   = (const float*)d_in[1];
    const float* adapter = (const float*)d_in[2];
    const float* conv_w  = (const float*)d_in[3];
    const float* conv_b  = (const float*)d_in[4];
    const float* mlp_w   = (const float*)d_in[5];
    const float* mlp_b   = (const float*)d_in[6];
    float* out = (float*)d_out;

    dim3 grid(NBLK);   // 800 blocks x 2 tiles; 80KB LDS -> 2 blocks/CU
    dim3 block(512);
    hipLaunchKernelGGL(mmf_kernel, grid, block, 0, stream,
                       feat0, feat1, adapter, conv_w, conv_b, mlp_w, mlp_b, out);
}

// Round 11
// 70.631 us; speedup vs baseline: 1.1990x; 1.1990x over previous
//
#include <hip/hip_runtime.h>

#define HW 25600
#define TS 16    // spatial locations per tile
#define NBLK 640 // 80 blocks per XCD; tiles stride-80 (2-3 per block)

typedef float  f32x4   __attribute__((ext_vector_type(4)));
typedef short  short8  __attribute__((ext_vector_type(8)));
typedef short  short4v __attribute__((ext_vector_type(4)));
typedef unsigned int uint2v __attribute__((ext_vector_type(2)));
typedef unsigned int uint4v __attribute__((ext_vector_type(4)));

__device__ __forceinline__ float bf2f(short h) {
    return __builtin_bit_cast(float, (unsigned)((unsigned short)h) << 16);
}
// HW packed f32->bf16 (RNE): D.lo = bf16(a), D.hi = bf16(b)
__device__ __forceinline__ unsigned cvt_pk(float a, float b) {
    unsigned r;
    asm("v_cvt_pk_bf16_f32 %0, %1, %2" : "=v"(r) : "v"(a), "v"(b));
    return r;
}

typedef __attribute__((address_space(3))) const char lds_cchar;
typedef __attribute__((address_space(3))) char lds_char;
typedef __attribute__((address_space(1))) const void g_cvoid;
__device__ __forceinline__ unsigned lds_u32(const void* p) {
    return (unsigned)(uintptr_t)(lds_cchar*)p;
}
// Async global->LDS DMA, 16B/lane. Dest = wave-uniform base + lane*16 (linear).
__device__ __forceinline__ void dma16(const float* g, unsigned lds_byte) {
    __builtin_amdgcn_global_load_lds(
        (g_cvoid*)g,
        (__attribute__((address_space(3))) void*)(lds_char*)(uintptr_t)lds_byte,
        16, 0, 0);
}

// ds_read_b64_tr_b16: lane addr = tile_base(128B-aligned) + lane16*8.
__device__ __forceinline__ short4v tr_read(unsigned a) {
    short4v d;
    asm volatile("ds_read_b64_tr_b16 %0, %1" : "=v"(d) : "v"(a) : "memory");
    return d;
}
__device__ __forceinline__ short4v tr_read128(unsigned a) {
    short4v d;
    asm volatile("ds_read_b64_tr_b16 %0, %1 offset:128" : "=v"(d) : "v"(a) : "memory");
    return d;
}
__device__ __forceinline__ uint4v lds_b128(unsigned a) {
    uint4v d;
    asm volatile("ds_read_b128 %0, %1" : "=v"(d) : "v"(a) : "memory");
    return d;
}
// Counted lgkm waits for the 2-deep DS pipelines (rule #18: SB(0) after).
__device__ __forceinline__ void wait_lgkm8() {
    asm volatile("s_waitcnt lgkmcnt(8)" ::: "memory");
    __builtin_amdgcn_sched_barrier(0);
}
__device__ __forceinline__ void wait_lgkm6() {
    asm volatile("s_waitcnt lgkmcnt(6)" ::: "memory");
    __builtin_amdgcn_sched_barrier(0);
}
__device__ __forceinline__ void wait_lgkm0() {
    asm volatile("s_waitcnt lgkmcnt(0)" ::: "memory");
    __builtin_amdgcn_sched_barrier(0);
}
// Barrier that drains only LDS ops; VMEM (DMA, stores) stays in flight.
__device__ __forceinline__ void bar_lgkm() {
    asm volatile("s_waitcnt lgkmcnt(0)" ::: "memory");
    __builtin_amdgcn_s_barrier();
    asm volatile("" ::: "memory");
}

// 8-read tr cluster: 4 tiles (t=0..3) x (lo, hi)
struct Clu { short4v lo0, hi0, lo1, hi1, lo2, hi2, lo3, hi3; };
__device__ __forceinline__ void issue_clu(Clu& C, unsigned base, int tstride) {
    C.lo0 = tr_read(base);                C.hi0 = tr_read128(base);
    C.lo1 = tr_read(base + tstride);      C.hi1 = tr_read128(base + tstride);
    C.lo2 = tr_read(base + 2 * tstride);  C.hi2 = tr_read128(base + 2 * tstride);
    C.lo3 = tr_read(base + 3 * tstride);  C.hi3 = tr_read128(base + 3 * tstride);
}
__device__ __forceinline__ short8 mk8(short4v lo, short4v hi) {
    return __builtin_shufflevector(lo, hi, 0, 1, 2, 3, 4, 5, 6, 7);
}

// LDS layout (bytes), 81920 total == 2 blocks/CU (163840 = full 160KiB pool):
//  Xbf  [4][256][16] bf16   0     .. 32768   feats (b-major), bf16
//    sc [32][16] f32 ALIASES [30720,32768) = Xbf b=3,m=1,k>=224. Safe:
//    scores' last read of that region precedes an intra-scores barrier,
//    sc's last read is in retrieved, and the only overwrite (next tile's
//    chunk 7) lands after the retrieved->MLP barrier.
//  fbf  [64][128]   bf16    32768 .. 49152   f (conv out), swizzle c^(s<<3)^(t<<5)
//  Rbf  [4][128][16] bf16   49152 .. 65536   retrieved
//  land 2 x 8KB             65536 .. 81920   rolling DMA chunk buffers
__global__ __launch_bounds__(512, 2) void mmf_kernel(
    const float* __restrict__ feat0, const float* __restrict__ feat1,
    const float* __restrict__ adapter, const float* __restrict__ conv_w,
    const float* __restrict__ conv_b, const float* __restrict__ mlp_w,
    const float* __restrict__ mlp_b, float* __restrict__ out)
{
    __shared__ __align__(128) char smem[81920];
    short* Xbf = (short*)smem;
    short* fbf = (short*)(smem + 32768);
    short* Rbf = (short*)(smem + 49152);
    float* sc  = (float*)(smem + 30720);   // aliases Xbf tail (see above)

    const int tid = threadIdx.x;
    const int bid = blockIdx.x;
    // XCD striping (R5-proven): XCD k = bid&7 owns tiles [200k,200k+200);
    // its 80 blocks take tiles jb, jb+80, jb+160(if jb<40). Adjacent tiles on
    // adjacent co-resident blocks -> both 64B halves of each 128B HBM line
    // are consumed from one L2 fetch. 16 extra blocks/XCD backfill via HW
    // dispatch as slots free (dynamic balance, no atomics).
    const int xcd  = bid & 7;
    const int jb   = bid >> 3;             // 0..79 within XCD
    const int tbeg = 200 * xcd + jb;
    const int tend = 200 * (xcd + 1);
    const int w   = __builtin_amdgcn_readfirstlane(tid >> 6); // wave id
    const int l   = tid & 63;
    const int g   = l >> 4;        // k-group within fragment
    const int sl  = l & 15;        // row/col-within-tile lane index
    const int c0  = w * 16;

    const unsigned xbase    = lds_u32(Xbf);
    const unsigned landbase = lds_u32(smem + 65536);

    // global source for chunk c of the tile at spatial offset S
    auto gsrc = [&](int c, int S) -> const float* {
        int idx = c * 512 + tid;          // [0,4096) float4 slots
        int q  = idx & 3;
        int r  = idx >> 2;
        int cc = r & 127;
        int b  = (r >> 7) & 3;
        int m  = r >> 9;
        const float* fp = m ? feat1 : feat0;
        return fp + (size_t)((b * 128 + cc) * HW + S + q * 4);
    };

    // One rolling-chunk step: wait oldest DMA, read 16B slot, reissue DMA
    // (chunk c+2 of this tile, or chunk c-6 of tile Snn), convert -> Xbf.
    // Chunk c covers Xbf region (b=c&3, m=c>>2); chunk 7 covers the sc alias.
    auto chunk_step = [&](int c, int Sn, int Snn, bool more) {
        if (c < 7 || more) { asm volatile("s_waitcnt vmcnt(1)" ::: "memory"); }
        else               { asm volatile("s_waitcnt vmcnt(0)" ::: "memory"); }
        __builtin_amdgcn_sched_barrier(0);
        const float4 v = *reinterpret_cast<const float4*>(
            smem + 65536 + (c & 1) * 8192 + tid * 16);
        asm volatile("s_waitcnt lgkmcnt(0)" ::: "memory");   // slot read done
        __builtin_amdgcn_sched_barrier(0);
        if (c <= 5)
            dma16(gsrc(c + 2, Sn), landbase + (unsigned)((c & 1) * 8192 + tid * 16));
        else if (more)
            dma16(gsrc(c - 6, Snn), landbase + (unsigned)((c & 1) * 8192 + tid * 16));
        int idx = c * 512 + tid;
        int q  = idx & 3;
        int r  = idx >> 2;
        int cc = r & 127;
        int b  = (r >> 7) & 3;
        int m  = r >> 9;
        uint2v xv;
        xv[0] = cvt_pk(v.x, v.y);
        xv[1] = cvt_pk(v.z, v.w);
        *reinterpret_cast<uint2v*>(Xbf + b * 4096 + (m * 128 + cc) * 16 + q * 4) = xv;
    };

    // ---------------- prologue: kick chunks 0,1; weights; burst tile0 -------
    const int S0 = tbeg * TS;
    dma16(gsrc(0, S0), landbase + (unsigned)(tid * 16));
    dma16(gsrc(1, S0), landbase + 8192u + (unsigned)(tid * 16));

    short8 afc[8];
    #pragma unroll
    for (int ks = 0; ks < 8; ++ks) {
        const int k0 = ks * 32 + g * 8;
        const float4 w0 = *reinterpret_cast<const float4*>(conv_w + (c0 + sl) * 256 + k0);
        const float4 w1 = *reinterpret_cast<const float4*>(conv_w + (c0 + sl) * 256 + k0 + 4);
        const float4 a0 = *reinterpret_cast<const float4*>(adapter + k0);
        const float4 a1 = *reinterpret_cast<const float4*>(adapter + k0 + 4);
        uint4v au;
        au[0] = cvt_pk(w0.x * a0.x, w0.y * a0.y);
        au[1] = cvt_pk(w0.z * a0.z, w0.w * a0.w);
        au[2] = cvt_pk(w1.x * a1.x, w1.y * a1.y);
        au[3] = cvt_pk(w1.z * a1.z, w1.w * a1.w);
        afc[ks] = __builtin_bit_cast(short8, au);
    }
    short8 afm[4];
    #pragma unroll
    for (int ks = 0; ks < 4; ++ks) {
        const int k0 = ks * 32 + g * 8;
        const float4 w0 = *reinterpret_cast<const float4*>(mlp_w + (c0 + sl) * 128 + k0);
        const float4 w1 = *reinterpret_cast<const float4*>(mlp_w + (c0 + sl) * 128 + k0 + 4);
        uint4v au;
        au[0] = cvt_pk(w0.x, w0.y);
        au[1] = cvt_pk(w0.z, w0.w);
        au[2] = cvt_pk(w1.x, w1.y);
        au[3] = cvt_pk(w1.z, w1.w);
        afm[ks] = __builtin_bit_cast(short8, au);
    }
    float bias[4], mb[4];
    #pragma unroll
    for (int i = 0; i < 4; ++i) {
        bias[i] = conv_b[c0 + g * 4 + i];
        mb[i]   = mlp_b[c0 + g * 4 + i];
    }
    {
        const bool more1 = (tbeg + 80) < tend;
        const int  S1    = (tbeg + 80) * TS;
        #pragma unroll
        for (int c = 0; c < 8; ++c) chunk_step(c, S0, S1, more1);
    }
    bar_lgkm();   // tile0 Xbf visible

    for (int ti = tbeg; ti < tend; ti += 80) {
        const int S    = ti * TS;
        const int tn   = ti + 80;           // tile being staged this iter
        const int tnn  = ti + 160;          // tile whose chunks 0,1 get issued
        const bool stg = tn < tend;
        const bool mr  = tnn < tend;

        // ---------------- conv via MFMA, 2-deep pipelined tr clusters --------
        {
            f32x4 acc[4] = {{0,0,0,0},{0,0,0,0},{0,0,0,0},{0,0,0,0}};
            Clu cA, cB;
            issue_clu(cA, xbase + 0 * 1024 + g * 256 + sl * 8, 8192);
            #pragma unroll
            for (int ks = 0; ks < 8; ++ks) {
                Clu& cur = (ks & 1) ? cB : cA;
                Clu& nxt = (ks & 1) ? cA : cB;
                if (ks < 7) {
                    issue_clu(nxt, xbase + (ks + 1) * 1024 + g * 256 + sl * 8, 8192);
                    wait_lgkm8();
                } else {
                    wait_lgkm0();
                }
                acc[0] = __builtin_amdgcn_mfma_f32_16x16x32_bf16(afc[ks], mk8(cur.lo0, cur.hi0), acc[0], 0, 0, 0);
                acc[1] = __builtin_amdgcn_mfma_f32_16x16x32_bf16(afc[ks], mk8(cur.lo1, cur.hi1), acc[1], 0, 0, 0);
                acc[2] = __builtin_amdgcn_mfma_f32_16x16x32_bf16(afc[ks], mk8(cur.lo2, cur.hi2), acc[2], 0, 0, 0);
                acc[3] = __builtin_amdgcn_mfma_f32_16x16x32_bf16(afc[ks], mk8(cur.lo3, cur.hi3), acc[3], 0, 0, 0);
            }
            #pragma unroll
            for (int tt = 0; tt < 4; ++tt) {
                const int col = tt * 16 + sl;
                uint2v fu;
                fu[0] = cvt_pk(acc[tt][0] + bias[0], acc[tt][1] + bias[1]);
                fu[1] = cvt_pk(acc[tt][2] + bias[2], acc[tt][3] + bias[3]);
                *reinterpret_cast<uint2v*>(fbf + col * 128 + (((c0 + g * 4) ^ (sl << 3)) ^ (tt << 5))) = fu;
            }
        }
        bar_lgkm();

        // -------- scores via MFMA + in-register softmax ----------------------
        {
            const int sm_m = w >> 2;
            const int sm_b = w & 3;
            const int ad = sl >> 2;
            const int aq = sl & 3;
            const unsigned fbase = lds_u32(fbf);
            const unsigned btile = xbase + sm_b * 8192 + sm_m * 4096 + g * 256 + sl * 8;
            f32x4 accS[4] = {{0,0,0,0},{0,0,0,0},{0,0,0,0},{0,0,0,0}};
            struct SC { short4v blo, bhi; uint4v a0, a1, a2, a3; };
            SC pA, pB;
            auto issue = [&](SC& Sv, int kk) {
                const unsigned bt = btile + (unsigned)(kk * 1024);
                Sv.blo = tr_read(bt); Sv.bhi = tr_read128(bt);
                const int cg = kk * 4 + g;
                Sv.a0 = lds_b128(fbase + (unsigned)((ad * 16 + 0 + aq) * 256 + (((cg ^ (0 + aq)) ^ (ad << 2)) << 4)));
                Sv.a1 = lds_b128(fbase + (unsigned)((ad * 16 + 4 + aq) * 256 + (((cg ^ (4 + aq)) ^ (ad << 2)) << 4)));
                Sv.a2 = lds_b128(fbase + (unsigned)((ad * 16 + 8 + aq) * 256 + (((cg ^ (8 + aq)) ^ (ad << 2)) << 4)));
                Sv.a3 = lds_b128(fbase + (unsigned)((ad * 16 + 12 + aq) * 256 + (((cg ^ (12 + aq)) ^ (ad << 2)) << 4)));
            };
            issue(pA, 0);
            #pragma unroll
            for (int kk = 0; kk < 4; ++kk) {
                SC& cur = (kk & 1) ? pB : pA;
                SC& nxt = (kk & 1) ? pA : pB;
                if (kk < 3) {
                    issue(nxt, kk + 1);
                    wait_lgkm6();
                } else {
                    wait_lgkm0();
                }
                const short8 bf = mk8(cur.blo, cur.bhi);
                accS[0] = __builtin_amdgcn_mfma_f32_16x16x32_bf16(__builtin_bit_cast(short8, cur.a0), bf, accS[0], 0, 0, 0);
                accS[1] = __builtin_amdgcn_mfma_f32_16x16x32_bf16(__builtin_bit_cast(short8, cur.a1), bf, accS[1], 0, 0, 0);
                accS[2] = __builtin_amdgcn_mfma_f32_16x16x32_bf16(__builtin_bit_cast(short8, cur.a2), bf, accS[2], 0, 0, 0);
                accS[3] = __builtin_amdgcn_mfma_f32_16x16x32_bf16(__builtin_bit_cast(short8, cur.a3), bf, accS[3], 0, 0, 0);
            }
            const int cstar = sl >> 2, qstar = sl & 3;
            float x = accS[0][0];
            #pragma unroll
            for (int c = 0; c < 4; ++c)
                #pragma unroll
                for (int q = 0; q < 4; ++q)
                    if (c == cstar && q == qstar) x = accS[c][q];
            x *= 0.088388347648318447f;   // 1/sqrt(128)
            float mx = fmaxf(x, __shfl_xor(x, 16));
            mx = fmaxf(mx, __shfl_xor(mx, 32));
            float e = __expf(x - mx);
            float sm = e + __shfl_xor(e, 16);
            sm += __shfl_xor(sm, 32);
            // sc aliases Xbf tail which scores READS above: barrier so all
            // waves' Xbf reads complete before any wave writes sc.
            bar_lgkm();
            sc[(sm_m * 16 + sm_b * 4 + g) * 16 + sl] = e / sm;
        }
        bar_lgkm();

        // ------- retrieved + (stg) chunks 0-3 of tile tn (Xbf m=0 zones) ----
        {
            const int b = l >> 4, s = l & 15;
            float aw[4];
            #pragma unroll
            for (int d = 0; d < 4; ++d)
                aw[d] = sc[(b * 4 + d) * 16 + s] + sc[(16 + b * 4 + d) * 16 + s];
            #pragma unroll
            for (int h = 0; h < 2; ++h) {
                const int cb = w * 2 + h;
                float r[8] = {0,0,0,0,0,0,0,0};
                #pragma unroll
                for (int d = 0; d < 4; ++d) {
                    const int colf = d * 16 + s;
                    short8 fv = *reinterpret_cast<const short8*>(
                        fbf + colf * 128 + (((cb ^ s) ^ (d << 2)) << 3));
                    #pragma unroll
                    for (int e = 0; e < 8; ++e) r[e] += aw[d] * bf2f(fv[e]);
                }
                #pragma unroll
                for (int e = 0; e < 8; e += 2) {
                    unsigned uu = cvt_pk(r[e], r[e + 1]);
                    Rbf[b * 2048 + (cb * 8 + e) * 16 + s]     = (short)(uu & 0xffffu);
                    Rbf[b * 2048 + (cb * 8 + e + 1) * 16 + s] = (short)(uu >> 16);
                }
            }
            if (stg) {
                #pragma unroll
                for (int c = 0; c < 4; ++c) chunk_step(c, tn * TS, tnn * TS, mr);
            }
        }
        bar_lgkm();

        // ------- MLP: (stg) chunks 4-7 of tn (incl. sc alias), then MFMA ----
        {
            if (stg) {
                #pragma unroll
                for (int c = 4; c < 8; ++c) chunk_step(c, tn * TS, tnn * TS, mr);
                wait_lgkm0();   // drain chunk ds_writes before counted waits
            }
            f32x4 acc[4] = {{0,0,0,0},{0,0,0,0},{0,0,0,0},{0,0,0,0}};
            const unsigned rbase = lds_u32(Rbf);
            Clu cA, cB;
            issue_clu(cA, rbase + 0 * 1024 + g * 256 + sl * 8, 4096);
            #pragma unroll
            for (int ks = 0; ks < 4; ++ks) {
                Clu& cur = (ks & 1) ? cB : cA;
                Clu& nxt = (ks & 1) ? cA : cB;
                if (ks < 3) {
                    issue_clu(nxt, rbase + (ks + 1) * 1024 + g * 256 + sl * 8, 4096);
                    wait_lgkm8();
                } else {
                    wait_lgkm0();
                }
                acc[0] = __builtin_amdgcn_mfma_f32_16x16x32_bf16(afm[ks], mk8(cur.lo0, cur.hi0), acc[0], 0, 0, 0);
                acc[1] = __builtin_amdgcn_mfma_f32_16x16x32_bf16(afm[ks], mk8(cur.lo1, cur.hi1), acc[1], 0, 0, 0);
                acc[2] = __builtin_amdgcn_mfma_f32_16x16x32_bf16(afm[ks], mk8(cur.lo2, cur.hi2), acc[2], 0, 0, 0);
                acc[3] = __builtin_amdgcn_mfma_f32_16x16x32_bf16(afm[ks], mk8(cur.lo3, cur.hi3), acc[3], 0, 0, 0);
            }
            // stores issue unwaited; the next tile's chunk vmcnt waits (or
            // s_endpgm) drain them off the critical path.
            #pragma unroll
            for (int tt = 0; tt < 4; ++tt) {
                const int col = tt * 16 + sl;    // b = tt, s = sl
                const short4v res = *reinterpret_cast<const short4v*>(
                    fbf + col * 128 + (((c0 + g * 4) ^ (sl << 3)) ^ (tt << 5)));
                #pragma unroll
                for (int i = 0; i < 4; ++i) {
                    const int c = c0 + g * 4 + i;
                    float v = fmaxf(acc[tt][i] + mb[i], 0.f) + bf2f(res[i]);
                    out[(size_t)(tt * 128 + c) * HW + S + sl] = v;
                }
            }
        }
        bar_lgkm();   // Xbf(tn) complete & visible; fbf/Rbf free for reuse
    }
}

extern "C" void kernel_launch(void* const* d_in, const int* in_sizes, int n_in,
                              void* d_out, int out_size, void* d_ws, size_t ws_size,
                              hipStream_t stream) {
    const float* feat0   = (const float*)d_in[0];
    const float* feat1   = (const float*)d_in[1];
    const float* adapter = (const float*)d_in[2];
    const float* conv_w  = (const float*)d_in[3];
    const float* conv_b  = (const float*)d_in[4];
    const float* mlp_w   = (const float*)d_in[5];
    const float* mlp_b   = (const float*)d_in[6];
    float* out = (float*)d_out;

    dim3 grid(NBLK);   // 640 blocks; 80KB LDS -> 2 blocks/CU; HW backfill
    dim3 block(512);
    hipLaunchKernelGGL(mmf_kernel, grid, block, 0, stream,
                       feat0, feat1, adapter, conv_w, conv_b, mlp_w, mlp_b, out);
}

// Round 12
// 49.028 us; speedup vs baseline: 1.7273x; 1.4406x over previous
//
#include <hip/hip_runtime.h>

#define HW 25600
#define TS 16   // spatial locations per tile
#define NT 1600 // total tiles
#define NB 256  // persistent blocks (1 per CU; LDS forces 1 block/CU)

typedef float  f32x4   __attribute__((ext_vector_type(4)));
typedef short  short8  __attribute__((ext_vector_type(8)));
typedef short  short4v __attribute__((ext_vector_type(4)));
typedef unsigned int uint2v __attribute__((ext_vector_type(2)));
typedef unsigned int uint4v __attribute__((ext_vector_type(4)));

__device__ __forceinline__ float bf2f(short h) {
    return __builtin_bit_cast(float, (unsigned)((unsigned short)h) << 16);
}
// HW packed f32->bf16 (RNE): D.lo = bf16(a), D.hi = bf16(b)
__device__ __forceinline__ unsigned cvt_pk(float a, float b) {
    unsigned r;
    asm("v_cvt_pk_bf16_f32 %0, %1, %2" : "=v"(r) : "v"(a), "v"(b));
    return r;
}

typedef __attribute__((address_space(3))) const char lds_cchar;
typedef __attribute__((address_space(3))) char lds_char;
typedef __attribute__((address_space(1))) const void g_cvoid;
__device__ __forceinline__ unsigned lds_u32(const void* p) {
    return (unsigned)(uintptr_t)(lds_cchar*)p;
}
// Async global->LDS DMA, 16B/lane. Dest = lds_base + lane*16 (linear);
// global source address is per-lane. No VGPR destination => no spill pressure.
__device__ __forceinline__ void dma16(const float* g, unsigned lds_byte) {
    __builtin_amdgcn_global_load_lds(
        (g_cvoid*)g,
        (__attribute__((address_space(3))) void*)(lds_char*)(uintptr_t)lds_byte,
        16, 0, 0);
}

// ds_read_b64_tr_b16: lane addr = tile_base(128B-aligned) + lane16*8.
// Elem j = bf16 at tile_base + lane16*2 + j*32. offset:128 -> next 4 rows.
__device__ __forceinline__ short4v tr_read(unsigned a) {
    short4v d;
    asm volatile("ds_read_b64_tr_b16 %0, %1" : "=v"(d) : "v"(a) : "memory");
    return d;
}
__device__ __forceinline__ short4v tr_read128(unsigned a) {
    short4v d;
    asm volatile("ds_read_b64_tr_b16 %0, %1 offset:128" : "=v"(d) : "v"(a) : "memory");
    return d;
}
__device__ __forceinline__ uint4v lds_b128(unsigned a) {
    uint4v d;
    asm volatile("ds_read_b128 %0, %1" : "=v"(d) : "v"(a) : "memory");
    return d;
}
// Counted lgkm waits for the 2-deep DS pipelines (rule #18: SB(0) after).
__device__ __forceinline__ void wait_lgkm8() {
    asm volatile("s_waitcnt lgkmcnt(8)" ::: "memory");
    __builtin_amdgcn_sched_barrier(0);
}
__device__ __forceinline__ void wait_lgkm6() {
    asm volatile("s_waitcnt lgkmcnt(6)" ::: "memory");
    __builtin_amdgcn_sched_barrier(0);
}
__device__ __forceinline__ void wait_lgkm0() {
    asm volatile("s_waitcnt lgkmcnt(0)" ::: "memory");
    __builtin_amdgcn_sched_barrier(0);
}
__device__ __forceinline__ void wait_vm0() {
    asm volatile("s_waitcnt vmcnt(0)" ::: "memory");
    __builtin_amdgcn_sched_barrier(0);
}
// Barrier that drains only LDS ops; VMEM (DMA, stores) stays in flight.
__device__ __forceinline__ void bar_lgkm() {
    asm volatile("s_waitcnt lgkmcnt(0)" ::: "memory");
    __builtin_amdgcn_s_barrier();
    asm volatile("" ::: "memory");
}

// 8-read tr cluster: 4 tiles (t=0..3) x (lo, hi)
struct Clu { short4v lo0, hi0, lo1, hi1, lo2, hi2, lo3, hi3; };
__device__ __forceinline__ void issue_clu(Clu& C, unsigned base, int tstride) {
    C.lo0 = tr_read(base);                C.hi0 = tr_read128(base);
    C.lo1 = tr_read(base + tstride);      C.hi1 = tr_read128(base + tstride);
    C.lo2 = tr_read(base + 2 * tstride);  C.hi2 = tr_read128(base + 2 * tstride);
    C.lo3 = tr_read(base + 3 * tstride);  C.hi3 = tr_read128(base + 3 * tstride);
}
__device__ __forceinline__ short8 mk8(short4v lo, short4v hi) {
    return __builtin_shufflevector(lo, hi, 0, 1, 2, 3, 4, 5, 6, 7);
}

// LDS layout (bytes), 133120 total (1 block/CU):
//  Xf32 [4096] float4      0      .. 65536   DMA landing buffer (f32, linear)
//  Xbf  [4][256][16] bf16   65536  .. 98304   feats (b-major), bf16
//  fbf  [64][128]   bf16    98304  .. 114688  f (conv out), swizzle c^(s<<3)^(t<<5)
//  Rbf  [4][128][16] bf16   114688 .. 131072  retrieved
//  sc   [32][16]    f32     131072 .. 133120  attn weights
__global__ __launch_bounds__(512, 2) void mmf_kernel(
    const float* __restrict__ feat0, const float* __restrict__ feat1,
    const float* __restrict__ adapter, const float* __restrict__ conv_w,
    const float* __restrict__ conv_b, const float* __restrict__ mlp_w,
    const float* __restrict__ mlp_b, float* __restrict__ out)
{
    __shared__ __align__(128) char smem[133120];
    float* Xf32 = (float*)smem;
    short* Xbf  = (short*)(smem + 65536);
    short* fbf  = (short*)(smem + 98304);
    short* Rbf  = (short*)(smem + 114688);
    float* sc   = (float*)(smem + 131072);

    const int tid = threadIdx.x;
    const int bid = blockIdx.x;
    // XCD-region striping (R5): XCD k (= bid&7) owns tiles [200k, 200k+200);
    // its 32 blocks stride by 32. Adjacent tiles run on adjacent blocks of the
    // SAME XCD concurrently -> both 64B halves of each 128B HBM line are
    // consumed from one L2 fetch.
    const int xcd  = bid & 7;
    const int jb   = bid >> 3;             // 0..31 within XCD
    const int tbeg = 200 * xcd + jb;
    const int tend = 200 * (xcd + 1);
    const int w   = __builtin_amdgcn_readfirstlane(tid >> 6); // wave id
    const int l   = tid & 63;
    const int g   = l >> 4;        // k-group within fragment
    const int sl  = l & 15;        // row/col-within-tile lane index
    const int c0  = w * 16;

    const unsigned xfbase = lds_u32(Xf32);
    const unsigned xbase  = lds_u32(Xbf);

    // ---- DMA issue for one tile at spatial offset S (async, no waits) ------
    auto stage_dma = [&](int S) {
        #pragma unroll
        for (int i = 0; i < 8; ++i) {
            int idx = i * 512 + tid;          // [0,4096) float4 slots
            int q  = idx & 3;
            int r  = idx >> 2;
            int cc = r & 127;
            int b  = (r >> 7) & 3;
            int m  = r >> 9;                  // wave-uniform (64-slot spans)
            const float* fp = m ? feat1 : feat0;
            // dest (uniform per wave+i): lane j lands at slot i*512+w*64+j
            dma16(fp + (size_t)((b * 128 + cc) * HW + S + q * 4),
                  xfbase + (unsigned)((i * 512 + (w << 6)) << 4));
        }
    };

    // ---------------- prologue: DMA first tile; build weight fragments ------
    stage_dma(tbeg * TS);

    short8 afc[8];
    #pragma unroll
    for (int ks = 0; ks < 8; ++ks) {
        const int k0 = ks * 32 + g * 8;
        const float4 w0 = *reinterpret_cast<const float4*>(conv_w + (c0 + sl) * 256 + k0);
        const float4 w1 = *reinterpret_cast<const float4*>(conv_w + (c0 + sl) * 256 + k0 + 4);
        const float4 a0 = *reinterpret_cast<const float4*>(adapter + k0);
        const float4 a1 = *reinterpret_cast<const float4*>(adapter + k0 + 4);
        uint4v au;
        au[0] = cvt_pk(w0.x * a0.x, w0.y * a0.y);
        au[1] = cvt_pk(w0.z * a0.z, w0.w * a0.w);
        au[2] = cvt_pk(w1.x * a1.x, w1.y * a1.y);
        au[3] = cvt_pk(w1.z * a1.z, w1.w * a1.w);
        afc[ks] = __builtin_bit_cast(short8, au);
    }
    short8 afm[4];
    #pragma unroll
    for (int ks = 0; ks < 4; ++ks) {
        const int k0 = ks * 32 + g * 8;
        const float4 w0 = *reinterpret_cast<const float4*>(mlp_w + (c0 + sl) * 128 + k0);
        const float4 w1 = *reinterpret_cast<const float4*>(mlp_w + (c0 + sl) * 128 + k0 + 4);
        uint4v au;
        au[0] = cvt_pk(w0.x, w0.y);
        au[1] = cvt_pk(w0.z, w0.w);
        au[2] = cvt_pk(w1.x, w1.y);
        au[3] = cvt_pk(w1.z, w1.w);
        afm[ks] = __builtin_bit_cast(short8, au);
    }
    float bias[4], mb[4];
    #pragma unroll
    for (int i = 0; i < 4; ++i) {
        bias[i] = conv_b[c0 + g * 4 + i];
        mb[i]   = mlp_b[c0 + g * 4 + i];
    }
    wait_vm0();     // DMA(first tile) + weight loads landed
    bar_lgkm();

    for (int ti = tbeg; ti < tend; ti += 32) {
        const int S = ti * TS;

        // ---- phase 1: convert Xf32 -> Xbf[b][m*128+cc][s] bf16 (LDS->LDS) --
        // No barrier precedes this on loop re-entry (R12 change): convert
        // touches only Xbf (dead since scores, all waves past retrieved bar)
        // and this wave's OWN Xf32 slots (drained by its wait_vm0 in MLP). A
        // fast wave overlapping convert(t+1) with a slow wave's MLP(t) is the
        // intended intra-block phase overlap.
        #pragma unroll
        for (int i = 0; i < 8; ++i) {
            int idx = i * 512 + tid;
            const float4 v = *reinterpret_cast<const float4*>(Xf32 + (size_t)idx * 4);
            int q  = idx & 3;
            int r  = idx >> 2;
            int cc = r & 127;
            int b  = (r >> 7) & 3;
            int m  = r >> 9;
            uint2v xv;
            xv[0] = cvt_pk(v.x, v.y);
            xv[1] = cvt_pk(v.z, v.w);
            *reinterpret_cast<uint2v*>(Xbf + b * 4096 + (m * 128 + cc) * 16 + q * 4) = xv;
        }
        bar_lgkm();   // Xbf visible; Xf32 free (all waves' reads drained)

        // ---- issue DMA for next tile (lands under the 4 compute phases) ----
        if (ti + 32 < tend) stage_dma((ti + 32) * TS);

        // ---------------- conv via MFMA, 2-deep pipelined tr clusters --------
        {
            f32x4 acc[4] = {{0,0,0,0},{0,0,0,0},{0,0,0,0},{0,0,0,0}};
            Clu cA, cB;
            issue_clu(cA, xbase + 0 * 1024 + g * 256 + sl * 8, 8192);
            #pragma unroll
            for (int ks = 0; ks < 8; ++ks) {
                Clu& cur = (ks & 1) ? cB : cA;
                Clu& nxt = (ks & 1) ? cA : cB;
                if (ks < 7) {
                    issue_clu(nxt, xbase + (ks + 1) * 1024 + g * 256 + sl * 8, 8192);
                    wait_lgkm8();
                } else {
                    wait_lgkm0();
                }
                acc[0] = __builtin_amdgcn_mfma_f32_16x16x32_bf16(afc[ks], mk8(cur.lo0, cur.hi0), acc[0], 0, 0, 0);
                acc[1] = __builtin_amdgcn_mfma_f32_16x16x32_bf16(afc[ks], mk8(cur.lo1, cur.hi1), acc[1], 0, 0, 0);
                acc[2] = __builtin_amdgcn_mfma_f32_16x16x32_bf16(afc[ks], mk8(cur.lo2, cur.hi2), acc[2], 0, 0, 0);
                acc[3] = __builtin_amdgcn_mfma_f32_16x16x32_bf16(afc[ks], mk8(cur.lo3, cur.hi3), acc[3], 0, 0, 0);
            }
            #pragma unroll
            for (int tt = 0; tt < 4; ++tt) {
                const int col = tt * 16 + sl;
                uint2v fu;
                fu[0] = cvt_pk(acc[tt][0] + bias[0], acc[tt][1] + bias[1]);
                fu[1] = cvt_pk(acc[tt][2] + bias[2], acc[tt][3] + bias[3]);
                *reinterpret_cast<uint2v*>(fbf + col * 128 + (((c0 + g * 4) ^ (sl << 3)) ^ (tt << 5))) = fu;
            }
        }
        bar_lgkm();

        // -------- scores via MFMA + in-register softmax ----------------------
        {
            const int sm_m = w >> 2;
            const int sm_b = w & 3;
            const int ad = sl >> 2;
            const int aq = sl & 3;
            const unsigned fbase = lds_u32(fbf);
            const unsigned btile = xbase + sm_b * 8192 + sm_m * 4096 + g * 256 + sl * 8;
            f32x4 accS[4] = {{0,0,0,0},{0,0,0,0},{0,0,0,0},{0,0,0,0}};
            struct SC { short4v blo, bhi; uint4v a0, a1, a2, a3; };
            SC pA, pB;
            auto issue = [&](SC& Sv, int kk) {
                const unsigned bt = btile + (unsigned)(kk * 1024);
                Sv.blo = tr_read(bt); Sv.bhi = tr_read128(bt);
                const int cg = kk * 4 + g;
                Sv.a0 = lds_b128(fbase + (unsigned)((ad * 16 + 0 + aq) * 256 + (((cg ^ (0 + aq)) ^ (ad << 2)) << 4)));
                Sv.a1 = lds_b128(fbase + (unsigned)((ad * 16 + 4 + aq) * 256 + (((cg ^ (4 + aq)) ^ (ad << 2)) << 4)));
                Sv.a2 = lds_b128(fbase + (unsigned)((ad * 16 + 8 + aq) * 256 + (((cg ^ (8 + aq)) ^ (ad << 2)) << 4)));
                Sv.a3 = lds_b128(fbase + (unsigned)((ad * 16 + 12 + aq) * 256 + (((cg ^ (12 + aq)) ^ (ad << 2)) << 4)));
            };
            issue(pA, 0);
            #pragma unroll
            for (int kk = 0; kk < 4; ++kk) {
                SC& cur = (kk & 1) ? pB : pA;
                SC& nxt = (kk & 1) ? pA : pB;
                if (kk < 3) {
                    issue(nxt, kk + 1);
                    wait_lgkm6();
                } else {
                    wait_lgkm0();
                }
                const short8 bf = mk8(cur.blo, cur.bhi);
                accS[0] = __builtin_amdgcn_mfma_f32_16x16x32_bf16(__builtin_bit_cast(short8, cur.a0), bf, accS[0], 0, 0, 0);
                accS[1] = __builtin_amdgcn_mfma_f32_16x16x32_bf16(__builtin_bit_cast(short8, cur.a1), bf, accS[1], 0, 0, 0);
                accS[2] = __builtin_amdgcn_mfma_f32_16x16x32_bf16(__builtin_bit_cast(short8, cur.a2), bf, accS[2], 0, 0, 0);
                accS[3] = __builtin_amdgcn_mfma_f32_16x16x32_bf16(__builtin_bit_cast(short8, cur.a3), bf, accS[3], 0, 0, 0);
            }
            const int cstar = sl >> 2, qstar = sl & 3;
            float x = accS[0][0];
            #pragma unroll
            for (int c = 0; c < 4; ++c)
                #pragma unroll
                for (int q = 0; q < 4; ++q)
                    if (c == cstar && q == qstar) x = accS[c][q];
            x *= 0.088388347648318447f;   // 1/sqrt(128)
            float mx = fmaxf(x, __shfl_xor(x, 16));
            mx = fmaxf(mx, __shfl_xor(mx, 32));
            float e = __expf(x - mx);
            float sm = e + __shfl_xor(e, 16);
            sm += __shfl_xor(sm, 32);
            sc[(sm_m * 16 + sm_b * 4 + g) * 16 + sl] = e / sm;
        }
        bar_lgkm();

        // ---------------- retrieved[col][cc] = sum_d aw[d]*f[(d,s)][cc] -----
        {
            const int b = l >> 4, s = l & 15;
            float aw[4];
            #pragma unroll
            for (int d = 0; d < 4; ++d)
                aw[d] = sc[(b * 4 + d) * 16 + s] + sc[(16 + b * 4 + d) * 16 + s];
            #pragma unroll
            for (int h = 0; h < 2; ++h) {
                const int cb = w * 2 + h;
                float r[8] = {0,0,0,0,0,0,0,0};
                #pragma unroll
                for (int d = 0; d < 4; ++d) {
                    const int colf = d * 16 + s;
                    short8 fv = *reinterpret_cast<const short8*>(
                        fbf + colf * 128 + (((cb ^ s) ^ (d << 2)) << 3));
                    #pragma unroll
                    for (int e = 0; e < 8; ++e) r[e] += aw[d] * bf2f(fv[e]);
                }
                #pragma unroll
                for (int e = 0; e < 8; e += 2) {
                    unsigned uu = cvt_pk(r[e], r[e + 1]);
                    Rbf[b * 2048 + (cb * 8 + e) * 16 + s]     = (short)(uu & 0xffffu);
                    Rbf[b * 2048 + (cb * 8 + e + 1) * 16 + s] = (short)(uu >> 16);
                }
            }
        }
        bar_lgkm();

        // ---------------- MLP via MFMA + relu + residual + out ---------------
        {
            f32x4 acc[4] = {{0,0,0,0},{0,0,0,0},{0,0,0,0},{0,0,0,0}};
            const unsigned rbase = lds_u32(Rbf);
            Clu cA, cB;
            issue_clu(cA, rbase + 0 * 1024 + g * 256 + sl * 8, 4096);
            #pragma unroll
            for (int ks = 0; ks < 4; ++ks) {
                Clu& cur = (ks & 1) ? cB : cA;
                Clu& nxt = (ks & 1) ? cA : cB;
                if (ks < 3) {
                    issue_clu(nxt, rbase + (ks + 1) * 1024 + g * 256 + sl * 8, 4096);
                    wait_lgkm8();
                } else {
                    wait_lgkm0();
                }
                acc[0] = __builtin_amdgcn_mfma_f32_16x16x32_bf16(afm[ks], mk8(cur.lo0, cur.hi0), acc[0], 0, 0, 0);
                acc[1] = __builtin_amdgcn_mfma_f32_16x16x32_bf16(afm[ks], mk8(cur.lo1, cur.hi1), acc[1], 0, 0, 0);
                acc[2] = __builtin_amdgcn_mfma_f32_16x16x32_bf16(afm[ks], mk8(cur.lo2, cur.hi2), acc[2], 0, 0, 0);
                acc[3] = __builtin_amdgcn_mfma_f32_16x16x32_bf16(afm[ks], mk8(cur.lo3, cur.hi3), acc[3], 0, 0, 0);
            }
            // Drain the next tile's DMA BEFORE issuing stores: per-wave vmcnt
            // then counts only DMA (stores not yet issued). The stores below
            // run unwaited and overlap the next tile's convert+conv phases.
            wait_vm0();
            #pragma unroll
            for (int tt = 0; tt < 4; ++tt) {
                const int col = tt * 16 + sl;    // b = tt, s = sl
                const short4v res = *reinterpret_cast<const short4v*>(
                    fbf + col * 128 + (((c0 + g * 4) ^ (sl << 3)) ^ (tt << 5)));
                #pragma unroll
                for (int i = 0; i < 4; ++i) {
                    const int c = c0 + g * 4 + i;
                    float v = fmaxf(acc[tt][i] + mb[i], 0.f) + bf2f(res[i]);
                    out[(size_t)(tt * 128 + c) * HW + S + sl] = v;
                }
            }
        }
        // R12: NO end-of-tile barrier. Next iteration's convert touches only
        // Xbf (dead) + this wave's own Xf32 slots (DMA drained by wait_vm0
        // above); fbf/Rbf are next written only after the convert-end barrier,
        // which no wave passes until all waves' MLP reads have drained.
    }
}

extern "C" void kernel_launch(void* const* d_in, const int* in_sizes, int n_in,
                              void* d_out, int out_size, void* d_ws, size_t ws_size,
                              hipStream_t stream) {
    const float* feat0   = (const float*)d_in[0];
    const float* feat1   = (const float*)d_in[1];
    const float* adapter = (const float*)d_in[2];
    const float* conv_w  = (const float*)d_in[3];
    const float* conv_b  = (const float*)d_in[4];
    const float* mlp_w   = (const float*)d_in[5];
    const float* mlp_b   = (const float*)d_in[6];
    float* out = (float*)d_out;

    dim3 grid(NB);     // 256 persistent blocks, 6-7 tiles each (XCD-striped)
    dim3 block(512);
    hipLaunchKernelGGL(mmf_kernel, grid, block, 0, stream,
                       feat0, feat1, adapter, conv_w, conv_b, mlp_w, mlp_b, out);
}